// Round 2
// baseline (902.178 us; speedup 1.0000x reference)
//
#include <hip/hip_runtime.h>
#include <hip/hip_bf16.h>
#include <stdint.h>

// QuantizedConv2d: x int8 (32,128,56,56), w int8 (256,128,3,3), pad 1, stride 1
// Harness passes integer inputs widened to int32; integer OUTPUT is read back as int32.

#define NB   32
#define CIN  128
#define HO   56
#define WO   56
#define KOUT 256
#define HP   58            // padded spatial (56 + 2)
#define KT   32            // output channels per conv block
#define KR   8             // output channels per thread

// ---------------- dot4 ----------------
#if __has_builtin(__builtin_amdgcn_sdot4)
static __device__ __forceinline__ int DOT4(int a, int b, int c) {
  return __builtin_amdgcn_sdot4(a, b, c, false);
}
#else
static __device__ __forceinline__ int DOT4(int a, int b, int c) {
  c += (int)(int8_t)(a      ) * (int)(int8_t)(b      );
  c += (int)(int8_t)(a >>  8) * (int)(int8_t)(b >>  8);
  c += (int)(int8_t)(a >> 16) * (int)(int8_t)(b >> 16);
  c += (int)(int8_t)(a >> 24) * (int)(int8_t)(b >> 24);
  return c;
}
#endif

// ---------------- zero padded-x buffer ----------------
// xp: int8 [NB][HP][HP][CIN] = 13,780,992 bytes = 861,312 int4 words
__global__ __launch_bounds__(256) void zero_xp_kernel(int8_t* __restrict__ xp) {
  const int idx = blockIdx.x * 256 + threadIdx.x;
  if (idx < (NB * HP * HP * CIN) / 16) {
    int4 z; z.x = 0; z.y = 0; z.z = 0; z.w = 0;
    reinterpret_cast<int4*>(xp)[idx] = z;
  }
}

// ---------------- pack x: NCHW int32 -> padded NHWC int8 ----------------
// grid (HO, NB), 256 threads; block handles one (n,h) row, all c, all w.
__global__ __launch_bounds__(256) void pack_x_kernel(const int* __restrict__ x,
                                                     int8_t* __restrict__ xp) {
  __shared__ int tile[WO][33];  // [w][c4], pad 33 to avoid bank conflicts
  const int tid = threadIdx.x;
  const int h = blockIdx.x;
  const int n = blockIdx.y;
  const int tx = tid & 63;      // w
  const int ty = tid >> 6;      // 0..3

  if (tx < WO) {
    #pragma unroll
    for (int c0 = 0; c0 < CIN; c0 += 16) {
      const int c = c0 + ty * 4;
      const int base = ((n * CIN + c) * HO + h) * WO + tx;
      const int v0 = x[base];
      const int v1 = x[base + HO * WO];
      const int v2 = x[base + 2 * HO * WO];
      const int v3 = x[base + 3 * HO * WO];
      const int w32 = (v0 & 0xff) | ((v1 & 0xff) << 8) | ((v2 & 0xff) << 16) | (v3 << 24);
      tile[tx][c >> 2] = w32;
    }
  }
  __syncthreads();
  // write 56*32 = 1792 int32 words, contiguous across lanes
  #pragma unroll
  for (int it = 0; it < 7; ++it) {
    const int i = it * 256 + tid;
    const int w = i >> 5;
    const int c4 = i & 31;
    const int v = tile[w][c4];
    *reinterpret_cast<int*>(xp + (((size_t)(n * HP + h + 1) * HP) + (w + 1)) * CIN + c4 * 4) = v;
  }
}

// ---------------- pack w: OIHW int32 -> [k][t][c] int8 ----------------
// 256*9*32 = 73,728 int32 words; grid 288 x 256
__global__ __launch_bounds__(256) void pack_w_kernel(const int* __restrict__ wgt,
                                                     int8_t* __restrict__ wp) {
  const int i = blockIdx.x * 256 + threadIdx.x;  // < 73728
  const int c4 = i & 31;
  const int t = (i >> 5) % 9;
  const int k = i / (32 * 9);
  const int base = (k * CIN + c4 * 4) * 9 + t;
  const int v0 = wgt[base];
  const int v1 = wgt[base + 9];
  const int v2 = wgt[base + 18];
  const int v3 = wgt[base + 27];
  const int w32 = (v0 & 0xff) | ((v1 & 0xff) << 8) | ((v2 & 0xff) << 16) | (v3 << 24);
  *reinterpret_cast<int*>(wp + (size_t)i * 4) = w32;
}

// ---------------- conv: dot4 inner loop ----------------
// grid (8 ktiles, 56 h, 32 n), 256 threads.
// Thread: pixel p = tid&63 (active p<56), wave kq = tid>>6, KR=8 channels each.
__global__ __launch_bounds__(256) void conv_kernel(const int8_t* __restrict__ xp,
                                                   const int8_t* __restrict__ wp,
                                                   const int* __restrict__ bias,
                                                   const float* __restrict__ wscale,
                                                   int* __restrict__ out) {
  __shared__ __align__(16) int8_t lx[3 * HP * CIN];   // 22,272 B (XOR-swizzled chunks)
  __shared__ __align__(16) int8_t lw[KT * 9 * CIN];   // 36,864 B

  const int tid = threadIdx.x;
  const int kt = blockIdx.x;
  const int h = blockIdx.y;
  const int n = blockIdx.z;
  const int k0 = kt * KT;

  // stage weights: 2304 int4 = 9 * 256
  {
    const int4* wg = reinterpret_cast<const int4*>(wp + (size_t)k0 * 9 * CIN);
    int4* wl = reinterpret_cast<int4*>(lw);
    #pragma unroll
    for (int i = 0; i < 9; ++i) wl[tid + i * 256] = wg[tid + i * 256];
  }
  // stage x rows h..h+2 (padded coords), 58 pixels x 128 c, XOR-swizzle chunk idx by pixel
  {
    const int8_t* xg = xp + (size_t)(n * HP + h) * HP * CIN;
    for (int i = tid; i < 3 * HP * 8; i += 256) {
      const int r = i / (HP * 8);
      const int rem = i - r * (HP * 8);
      const int q = rem >> 3;
      const int cc = rem & 7;
      const int4 v = *reinterpret_cast<const int4*>(xg + (r * HP + q) * CIN + (cc << 4));
      *reinterpret_cast<int4*>(lx + (r * HP + q) * CIN + ((cc ^ (q & 7)) << 4)) = v;
    }
  }
  __syncthreads();

  const int p = tid & 63;
  const int kq = tid >> 6;
  const int pw = (p < WO) ? p : 0;

  int acc[KR];
  #pragma unroll
  for (int j = 0; j < KR; ++j) acc[j] = 0;

  #pragma unroll
  for (int kh = 0; kh < 3; ++kh) {
    #pragma unroll
    for (int kw = 0; kw < 3; ++kw) {
      const int pix = pw + kw;
      const int8_t* xb = lx + (kh * HP + pix) * CIN;
      const int xs = pix & 7;
      const int8_t* wb = lw + (kq * KR * 9 + kh * 3 + kw) * CIN;
      #pragma unroll
      for (int cc = 0; cc < 8; ++cc) {
        const int4 xv = *reinterpret_cast<const int4*>(xb + ((cc ^ xs) << 4));
        #pragma unroll
        for (int j = 0; j < KR; ++j) {
          const int4 wv = *reinterpret_cast<const int4*>(wb + j * 9 * CIN + (cc << 4));
          acc[j] = DOT4(xv.x, wv.x, acc[j]);
          acc[j] = DOT4(xv.y, wv.y, acc[j]);
          acc[j] = DOT4(xv.z, wv.z, acc[j]);
          acc[j] = DOT4(xv.w, wv.w, acc[j]);
        }
      }
    }
  }

  if (p < WO) {
    #pragma unroll
    for (int j = 0; j < KR; ++j) {
      const int k = k0 + kq * KR + j;
      const float scale = (0.02f * wscale[k]) / 0.05f;  // IN_SCALE * ws / OUT_SCALE
      float v = (float)(acc[j] + bias[k]) * scale;      // + OUT_ZP (=0)
      v = rintf(v);                                     // round-half-even == jnp.round
      v = fminf(fmaxf(v, -128.0f), 127.0f);
      out[(((size_t)n * KOUT + k) * HO + h) * WO + p] = (int)v;  // int32 output!
    }
  }
}

extern "C" void kernel_launch(void* const* d_in, const int* in_sizes, int n_in,
                              void* d_out, int out_size, void* d_ws, size_t ws_size,
                              hipStream_t stream) {
  const int* x = (const int*)d_in[0];
  const int* wgt = (const int*)d_in[1];
  const int* bias = (const int*)d_in[2];
  const float* wscale = (const float*)d_in[3];
  int* out = (int*)d_out;

  int8_t* xp = (int8_t*)d_ws;                          // 13,780,992 B
  int8_t* wp = (int8_t*)d_ws + (size_t)NB * HP * HP * CIN;  // 294,912 B

  const int zero_words = (NB * HP * HP * CIN) / 16;    // 861,312
  zero_xp_kernel<<<(zero_words + 255) / 256, 256, 0, stream>>>(xp);
  pack_x_kernel<<<dim3(HO, NB), 256, 0, stream>>>(x, xp);
  pack_w_kernel<<<288, 256, 0, stream>>>(wgt, wp);
  conv_kernel<<<dim3(KOUT / KT, HO, NB), 256, 0, stream>>>(xp, wp, bias, wscale, out);
}

// Round 3
// 236.963 us; speedup vs baseline: 3.8073x; 3.8073x over previous
//
#include <hip/hip_runtime.h>
#include <hip/hip_bf16.h>
#include <stdint.h>

// QuantizedConv2d int8: x (32,128,56,56), w (256,128,3,3), pad 1, stride 1.
// Implicit GEMM on v_mfma_i32_32x32x32_i8. M=pixels, N=256 ch, K=9*128=1152.

#define NB   32
#define CIN  128
#define HO   56
#define WO   56
#define KOUT 256
#define HP   58
#define ROWB (HP * CIN)          // 7424 bytes per padded row

typedef int v4i  __attribute__((ext_vector_type(4)));
typedef int v16i __attribute__((ext_vector_type(16)));

// ---------------- zero padded-x buffer ----------------
__global__ __launch_bounds__(256) void zero_xp_kernel(int8_t* __restrict__ xp) {
  const int idx = blockIdx.x * 256 + threadIdx.x;
  if (idx < (NB * HP * ROWB) / 16) {
    int4 z; z.x = 0; z.y = 0; z.z = 0; z.w = 0;
    reinterpret_cast<int4*>(xp)[idx] = z;
  }
}

// ---------------- pack x: NCHW int32 -> padded NHWC int8 (linear) ----------------
__global__ __launch_bounds__(256) void pack_x_kernel(const int* __restrict__ x,
                                                     int8_t* __restrict__ xp) {
  __shared__ int tile[WO][33];
  const int tid = threadIdx.x;
  const int h = blockIdx.x;
  const int n = blockIdx.y;
  const int tx = tid & 63;
  const int ty = tid >> 6;

  if (tx < WO) {
    #pragma unroll
    for (int c0 = 0; c0 < CIN; c0 += 16) {
      const int c = c0 + ty * 4;
      const int base = ((n * CIN + c) * HO + h) * WO + tx;
      const int v0 = x[base];
      const int v1 = x[base + HO * WO];
      const int v2 = x[base + 2 * HO * WO];
      const int v3 = x[base + 3 * HO * WO];
      const int w32 = (v0 & 0xff) | ((v1 & 0xff) << 8) | ((v2 & 0xff) << 16) | (v3 << 24);
      tile[tx][c >> 2] = w32;
    }
  }
  __syncthreads();
  #pragma unroll
  for (int it = 0; it < 7; ++it) {
    const int i = it * 256 + tid;
    const int w = i >> 5;
    const int c4 = i & 31;
    *reinterpret_cast<int*>(xp + ((size_t)(n * HP + h + 1) * HP + (w + 1)) * CIN + c4 * 4)
        = tile[w][c4];
  }
}

// ---------------- pack w: OIHW int32 -> [kt(2)][tap(9)][slot(1024)] int8 chunks ----
// LDS slot s holds channel-chunk c = (s&7) ^ ((s>>3)&7) of output channel n = s>>3,
// i.e. weights land in LDS pre-swizzled by a plain linear copy.
__global__ __launch_bounds__(256) void pack_w_kernel(const int* __restrict__ wgt,
                                                     int8_t* __restrict__ wq) {
  const int wid = blockIdx.x * 256 + threadIdx.x;   // 0..73727 (int32 words)
  const int wi = wid & 3;                           // word within 16B chunk
  const int ci = wid >> 2;                          // chunk 0..18431
  const int kt = ci / 9216;
  const int r  = ci - kt * 9216;
  const int tap = r >> 10;
  const int s   = r & 1023;
  const int n  = s >> 3;
  const int c  = (s & 7) ^ (n & 7);                 // logical channel chunk
  const int k  = kt * 128 + n;
  const int c0 = c * 16 + wi * 4;
  const int base = (k * CIN + c0) * 9 + tap;        // OIHW, 3x3=9 taps
  const int v0 = wgt[base];
  const int v1 = wgt[base + 9];
  const int v2 = wgt[base + 18];
  const int v3 = wgt[base + 27];
  reinterpret_cast<int*>(wq)[wid] =
      (v0 & 0xff) | ((v1 & 0xff) << 8) | ((v2 & 0xff) << 16) | (v3 << 24);
}

// ---------------- conv: MFMA implicit GEMM ----------------
// grid (2 ktiles, 28 rowpairs, 32 n), 256 threads (4 waves).
// Block: M=128 px (2 output rows x 64, 56 valid), N=128 ch, K=1152 looped per tap.
// Wave (wm,wn): M 64 (one row, 2 tiles) x N 64 (2 tiles). 1 ds_read_b128 per MFMA.
__global__ __launch_bounds__(256) void conv_kernel(const int8_t* __restrict__ xp,
                                                   const int8_t* __restrict__ wq,
                                                   const int* __restrict__ bias,
                                                   const float* __restrict__ wscale,
                                                   int* __restrict__ out) {
  __shared__ __align__(16) int8_t lx[240 * CIN];      // 30720 B: 4 rows x 58 px (+slack)
  __shared__ __align__(16) int8_t lw[2 * 128 * CIN];  // 32768 B: double-buffered tap

  const int tid = threadIdx.x;
  const int kt = blockIdx.x;
  const int h0 = blockIdx.y * 2;                      // first output row
  const int n_img = blockIdx.z;

  const int lane = tid & 63;
  const int wid = tid >> 6;
  const int wm = wid & 1;                             // which output row
  const int wn = wid >> 1;                            // which 64-ch half
  const int p0 = lane & 31;
  const int half = lane >> 5;

  const int4* wqt = reinterpret_cast<const int4*>(wq + (size_t)kt * 9216 * 16);
  const int8_t* xg = xp + ((size_t)(n_img * HP) + h0) * ROWB;

  // ---- stage x: 4 padded rows, linear copy with flat-pixel XOR swizzle ----
  #pragma unroll
  for (int it = 0; it < 8; ++it) {
    const int i = it * 256 + tid;                     // chunk slot, < 1856
    if (i < 4 * HP * 8) {
      const int pf = i >> 3;
      const int cc = (i & 7) ^ (pf & 7);
      const int4 v = *reinterpret_cast<const int4*>(xg + pf * CIN + (cc << 4));
      *reinterpret_cast<int4*>(lx + i * 16) = v;
    }
  }
  // ---- stage weights tap 0 into buf 0 ----
  #pragma unroll
  for (int j = 0; j < 4; ++j) {
    const int s = j * 256 + tid;
    const int4 v = wqt[s];
    *reinterpret_cast<int4*>(lw + s * 16) = v;
  }
  // ---- prefetch tap 1 into regs ----
  int4 wreg[4];
  #pragma unroll
  for (int j = 0; j < 4; ++j) wreg[j] = wqt[1024 + j * 256 + tid];
  __syncthreads();

  v16i acc[2][2];
  #pragma unroll
  for (int mt = 0; mt < 2; ++mt)
    #pragma unroll
    for (int nt = 0; nt < 2; ++nt)
      #pragma unroll
      for (int e = 0; e < 16; ++e) acc[mt][nt][e] = 0;

  const int base0 = wm * HP + p0;                     // flat pixel (row wm, px p0)
  const int nl0 = wn * 64 + p0;                       // n_local base
  const int keyb = (p0 & 7) << 4;

  #pragma unroll
  for (int tap = 0; tap < 9; ++tap) {
    // write next tap's weights (prefetched last iter) into the other buffer
    if (tap < 8) {
      #pragma unroll
      for (int j = 0; j < 4; ++j) {
        const int s = j * 256 + tid;
        *reinterpret_cast<int4*>(lw + ((tap + 1) & 1) * 16384 + s * 16) = wreg[j];
      }
    }
    if (tap < 7) {
      #pragma unroll
      for (int j = 0; j < 4; ++j) wreg[j] = wqt[(tap + 2) * 1024 + j * 256 + tid];
    }

    const int kh = tap / 3, kw = tap % 3;
    const int pfb = base0 + kh * HP + kw;             // flat pixel for mt=0
    const int keya = ((pfb & 7)) << 4;                // swizzle key (mt*32 == 0 mod 8)
    const int8_t* lwb = lw + (tap & 1) * 16384;

    #pragma unroll
    for (int ks = 0; ks < 4; ++ks) {
      const int ch = ((ks * 2 + half) << 4);          // chunk byte offset pre-shift
      v4i a[2], b[2];
      #pragma unroll
      for (int mt = 0; mt < 2; ++mt)
        a[mt] = *reinterpret_cast<const v4i*>(lx + (pfb + mt * 32) * CIN + (ch ^ keya));
      #pragma unroll
      for (int nt = 0; nt < 2; ++nt)
        b[nt] = *reinterpret_cast<const v4i*>(lwb + (nl0 + nt * 32) * CIN + (ch ^ keyb));
      acc[0][0] = __builtin_amdgcn_mfma_i32_32x32x32_i8(a[0], b[0], acc[0][0], 0, 0, 0);
      acc[0][1] = __builtin_amdgcn_mfma_i32_32x32x32_i8(a[0], b[1], acc[0][1], 0, 0, 0);
      acc[1][0] = __builtin_amdgcn_mfma_i32_32x32x32_i8(a[1], b[0], acc[1][0], 0, 0, 0);
      acc[1][1] = __builtin_amdgcn_mfma_i32_32x32x32_i8(a[1], b[1], acc[1][1], 0, 0, 0);
    }
    __syncthreads();
  }

  // ---- epilogue: requant + store (D: m=(reg&3)+8*(reg>>2)+4*half, n=lane&31) ----
  const int h = h0 + wm;
  #pragma unroll
  for (int nt = 0; nt < 2; ++nt) {
    const int ch = kt * 128 + wn * 64 + nt * 32 + p0;
    const int bi = bias[ch];
    const float sc = (0.02f * wscale[ch]) / 0.05f;
    int* ob = out + (((size_t)n_img * KOUT + ch) * HO + h) * WO;
    #pragma unroll
    for (int mt = 0; mt < 2; ++mt) {
      #pragma unroll
      for (int r = 0; r < 16; ++r) {
        const int m = (r & 3) + 8 * (r >> 2) + 4 * half;
        const int w = mt * 32 + m;
        if (w < WO) {
          float v = (float)(acc[mt][nt][r] + bi) * sc;
          v = rintf(v);
          v = fminf(fmaxf(v, -128.0f), 127.0f);
          ob[w] = (int)v;
        }
      }
    }
  }
}

extern "C" void kernel_launch(void* const* d_in, const int* in_sizes, int n_in,
                              void* d_out, int out_size, void* d_ws, size_t ws_size,
                              hipStream_t stream) {
  const int* x = (const int*)d_in[0];
  const int* wgt = (const int*)d_in[1];
  const int* bias = (const int*)d_in[2];
  const float* wscale = (const float*)d_in[3];
  int* out = (int*)d_out;

  int8_t* xp = (int8_t*)d_ws;                               // 13,780,992 B
  int8_t* wq = (int8_t*)d_ws + (size_t)NB * HP * ROWB;      // 294,912 B

  const int zero_words = (NB * HP * ROWB) / 16;
  zero_xp_kernel<<<(zero_words + 255) / 256, 256, 0, stream>>>(xp);
  pack_x_kernel<<<dim3(HO, NB), 256, 0, stream>>>(x, xp);
  pack_w_kernel<<<288, 256, 0, stream>>>(wgt, wq);
  conv_kernel<<<dim3(2, 28, 32), 256, 0, stream>>>(xp, wq, bias, wscale, out);
}

// Round 4
// 226.191 us; speedup vs baseline: 3.9886x; 1.0476x over previous
//
#include <hip/hip_runtime.h>
#include <hip/hip_bf16.h>
#include <stdint.h>

// QuantizedConv2d int8: x (32,128,56,56), w (256,128,3,3), pad 1, stride 1.
// Implicit GEMM on v_mfma_i32_32x32x32_i8. M=pixels, N=256 ch, K=9*128=1152.
// R4: A from LDS (staged once, 1 barrier), B direct from global (L1/L2-hot),
//     no K-loop barriers, occupancy 16 waves/CU, zero-pass fused into pack_x.

#define NB   32
#define CIN  128
#define HO   56
#define WO   56
#define KOUT 256
#define HP   58
#define ROWB (HP * CIN)          // 7424 bytes per padded row

typedef int v4i  __attribute__((ext_vector_type(4)));
typedef int v16i __attribute__((ext_vector_type(16)));

// ---------------- pack x: NCHW int32 -> padded NHWC int8, borders written ----
// grid (HP, NB): block writes one full padded row (58 px x 128 c), zeros on borders.
__global__ __launch_bounds__(256) void pack_x_kernel(const int* __restrict__ x,
                                                     int8_t* __restrict__ xp) {
  __shared__ int tile[WO][33];
  const int tid = threadIdx.x;
  const int r = blockIdx.x;          // padded row 0..57
  const int n = blockIdx.y;
  const int tx = tid & 63;
  const int ty = tid >> 6;
  const bool interior = (r >= 1) && (r <= HO);

  if (interior && tx < WO) {
    const int h = r - 1;
    #pragma unroll
    for (int c0 = 0; c0 < CIN; c0 += 16) {
      const int c = c0 + ty * 4;
      const int base = ((n * CIN + c) * HO + h) * WO + tx;
      const int v0 = x[base];
      const int v1 = x[base + HO * WO];
      const int v2 = x[base + 2 * HO * WO];
      const int v3 = x[base + 3 * HO * WO];
      tile[tx][c >> 2] = (v0 & 0xff) | ((v1 & 0xff) << 8) | ((v2 & 0xff) << 16) | (v3 << 24);
    }
  }
  __syncthreads();
  // write 58*32 = 1856 int32 words for this padded row
  #pragma unroll
  for (int it = 0; it < 8; ++it) {
    const int i = it * 256 + tid;
    if (i < HP * 32) {
      const int w = i >> 5;          // padded col 0..57
      const int c4 = i & 31;
      const int v = (interior && w >= 1 && w <= WO) ? tile[w - 1][c4] : 0;
      *reinterpret_cast<int*>(xp + ((size_t)(n * HP + r) * HP + w) * CIN + c4 * 4) = v;
    }
  }
}

// ---------------- pack w: OIHW int32 -> [kt(2)][tap(9)][n(128)][chunk(8)] 16B ----
__global__ __launch_bounds__(256) void pack_w_kernel(const int* __restrict__ wgt,
                                                     int8_t* __restrict__ wq) {
  const int wid = blockIdx.x * 256 + threadIdx.x;   // 0..73727 int32 words
  const int wi = wid & 3;
  const int ci = wid >> 2;                          // chunk 0..18431
  const int c   = ci & 7;
  const int nch = (ci >> 3) & 127;
  const int tt  = ci >> 10;                         // kt*9 + tap
  const int tap = tt % 9;
  const int kt  = tt / 9;
  const int k  = kt * 128 + nch;
  const int c0 = c * 16 + wi * 4;
  const int base = (k * CIN + c0) * 9 + tap;        // OIHW, 3x3=9 taps
  const int v0 = wgt[base];
  const int v1 = wgt[base + 9];
  const int v2 = wgt[base + 18];
  const int v3 = wgt[base + 27];
  reinterpret_cast<int*>(wq)[wid] =
      (v0 & 0xff) | ((v1 & 0xff) << 8) | ((v2 & 0xff) << 16) | (v3 << 24);
}

// ---------------- conv: MFMA implicit GEMM, A in LDS, B from global ----------
// grid (28 rowpairs, 32 n, 2 kt), 256 threads (4 waves).
// Block: M=128 px (2 output rows x 64, 56 valid), N=128 ch, K=1152.
// Wave (wm,wn): 64x64 = 2x2 tiles of 32x32. One barrier total.
__global__ __launch_bounds__(256, 4) void conv_kernel(const int8_t* __restrict__ xp,
                                                      const int8_t* __restrict__ wq,
                                                      const int* __restrict__ bias,
                                                      const float* __restrict__ wscale,
                                                      int* __restrict__ out) {
  __shared__ __align__(16) int8_t lx[4 * HP * 8 * 16];   // 29,696 B: 4 padded rows

  const int tid = threadIdx.x;
  const int h0 = blockIdx.x * 2;
  const int n_img = blockIdx.y;
  const int kt = blockIdx.z;

  const int lane = tid & 63;
  const int wid = tid >> 6;
  const int wm = wid & 1;
  const int wn = wid >> 1;
  const int p0 = lane & 31;
  const int half = lane >> 5;

  const int8_t* xg = xp + ((size_t)(n_img * HP) + h0) * ROWB;
  const int8_t* wbase = wq + (size_t)kt * 9216 * 16;     // this kt's 147,456 B

  // ---- stage x: 4 padded rows, flat-pixel XOR chunk swizzle ----
  #pragma unroll
  for (int it = 0; it < 8; ++it) {
    const int i = it * 256 + tid;                        // chunk slot < 1856
    if (i < 4 * HP * 8) {
      const int pf = i >> 3;
      const int cc = (i & 7) ^ (pf & 7);
      const int4 v = *reinterpret_cast<const int4*>(xg + pf * CIN + (cc << 4));
      *reinterpret_cast<int4*>(lx + i * 16) = v;
    }
  }
  __syncthreads();

  v16i acc[2][2];
  #pragma unroll
  for (int mt = 0; mt < 2; ++mt)
    #pragma unroll
    for (int nt = 0; nt < 2; ++nt)
      #pragma unroll
      for (int e = 0; e < 16; ++e) acc[mt][nt][e] = 0;

  const int base0 = wm * HP + p0;                        // flat pixel (row wm, px p0)
  // B lane base byte offsets within a tap tile (constant over taps/ks)
  const int8_t* bp0 = wbase + (wn * 64 + p0) * 128 + half * 16;
  const int8_t* bp1 = bp0 + 32 * 128;

  #pragma unroll
  for (int tap = 0; tap < 9; ++tap) {
    const int kh = tap / 3, kw = tap % 3;
    const int pfb = base0 + kh * HP + kw;
    const int keya = (pfb & 7) << 4;
    const int tapoff = tap * 16384;

    #pragma unroll
    for (int ks = 0; ks < 4; ++ks) {
      const int ch = (ks * 2 + half) << 4;
      v4i a[2], b[2];
      #pragma unroll
      for (int mt = 0; mt < 2; ++mt)
        a[mt] = *reinterpret_cast<const v4i*>(lx + (pfb + mt * 32) * CIN + (ch ^ keya));
      b[0] = *reinterpret_cast<const v4i*>(bp0 + tapoff + ks * 32);
      b[1] = *reinterpret_cast<const v4i*>(bp1 + tapoff + ks * 32);
      acc[0][0] = __builtin_amdgcn_mfma_i32_32x32x32_i8(a[0], b[0], acc[0][0], 0, 0, 0);
      acc[0][1] = __builtin_amdgcn_mfma_i32_32x32x32_i8(a[0], b[1], acc[0][1], 0, 0, 0);
      acc[1][0] = __builtin_amdgcn_mfma_i32_32x32x32_i8(a[1], b[0], acc[1][0], 0, 0, 0);
      acc[1][1] = __builtin_amdgcn_mfma_i32_32x32x32_i8(a[1], b[1], acc[1][1], 0, 0, 0);
    }
  }

  // ---- epilogue: requant + store (D: m=(reg&3)+8*(reg>>2)+4*half, n=lane&31) ----
  const int h = h0 + wm;
  #pragma unroll
  for (int nt = 0; nt < 2; ++nt) {
    const int ch = kt * 128 + wn * 64 + nt * 32 + p0;
    const int bi = bias[ch];
    const float sc = (0.02f * wscale[ch]) / 0.05f;
    int* ob = out + (((size_t)n_img * KOUT + ch) * HO + h) * WO;
    #pragma unroll
    for (int mt = 0; mt < 2; ++mt) {
      #pragma unroll
      for (int r = 0; r < 16; ++r) {
        const int m = (r & 3) + 8 * (r >> 2) + 4 * half;
        const int w = mt * 32 + m;
        if (w < WO) {
          float v = (float)(acc[mt][nt][r] + bi) * sc;
          v = rintf(v);
          v = fminf(fmaxf(v, -128.0f), 127.0f);
          ob[w] = (int)v;
        }
      }
    }
  }
}

extern "C" void kernel_launch(void* const* d_in, const int* in_sizes, int n_in,
                              void* d_out, int out_size, void* d_ws, size_t ws_size,
                              hipStream_t stream) {
  const int* x = (const int*)d_in[0];
  const int* wgt = (const int*)d_in[1];
  const int* bias = (const int*)d_in[2];
  const float* wscale = (const float*)d_in[3];
  int* out = (int*)d_out;

  int8_t* xp = (int8_t*)d_ws;                               // 13,780,992 B
  int8_t* wq = (int8_t*)d_ws + (size_t)NB * HP * ROWB;      // 294,912 B

  pack_x_kernel<<<dim3(HP, NB), 256, 0, stream>>>(x, xp);
  pack_w_kernel<<<288, 256, 0, stream>>>(wgt, wq);
  conv_kernel<<<dim3(28, 32, 2), 256, 0, stream>>>(xp, wq, bias, wscale, out);
}

// Round 5
// 217.899 us; speedup vs baseline: 4.1404x; 1.0381x over previous
//
#include <hip/hip_runtime.h>
#include <hip/hip_bf16.h>
#include <stdint.h>

// QuantizedConv2d int8: x (32,128,56,56), w (256,128,3,3), pad 1, stride 1.
// Implicit GEMM on v_mfma_i32_32x32x32_i8. M=256 out-ch, N=pixels, K=9*128=1152.
// R5: A-operand = weights (register double-buffered, tap-ahead prefetch from L2),
//     B-operand = pixels (LDS, staged once). D col = pixel -> coalesced stores.

#define NB   32
#define CIN  128
#define HO   56
#define WO   56
#define KOUT 256
#define HP   58
#define ROWB (HP * CIN)          // 7424 bytes per padded row

typedef int v4i  __attribute__((ext_vector_type(4)));
typedef int v16i __attribute__((ext_vector_type(16)));

// ---------------- pack x: NCHW int32 -> padded NHWC int8, borders written ----
__global__ __launch_bounds__(256) void pack_x_kernel(const int* __restrict__ x,
                                                     int8_t* __restrict__ xp) {
  __shared__ int tile[WO][33];
  const int tid = threadIdx.x;
  const int r = blockIdx.x;          // padded row 0..57
  const int n = blockIdx.y;
  const int tx = tid & 63;
  const int ty = tid >> 6;
  const bool interior = (r >= 1) && (r <= HO);

  if (interior && tx < WO) {
    const int h = r - 1;
    #pragma unroll
    for (int c0 = 0; c0 < CIN; c0 += 16) {
      const int c = c0 + ty * 4;
      const int base = ((n * CIN + c) * HO + h) * WO + tx;
      const int v0 = x[base];
      const int v1 = x[base + HO * WO];
      const int v2 = x[base + 2 * HO * WO];
      const int v3 = x[base + 3 * HO * WO];
      tile[tx][c >> 2] = (v0 & 0xff) | ((v1 & 0xff) << 8) | ((v2 & 0xff) << 16) | (v3 << 24);
    }
  }
  __syncthreads();
  #pragma unroll
  for (int it = 0; it < 8; ++it) {
    const int i = it * 256 + tid;
    if (i < HP * 32) {
      const int w = i >> 5;
      const int c4 = i & 31;
      const int v = (interior && w >= 1 && w <= WO) ? tile[w - 1][c4] : 0;
      *reinterpret_cast<int*>(xp + ((size_t)(n * HP + r) * HP + w) * CIN + c4 * 4) = v;
    }
  }
}

// ---------------- pack w: OIHW int32 -> [kt(2)][tap(9)][n(128)][chunk(8)] 16B ----
__global__ __launch_bounds__(256) void pack_w_kernel(const int* __restrict__ wgt,
                                                     int8_t* __restrict__ wq) {
  const int wid = blockIdx.x * 256 + threadIdx.x;   // 0..73727 int32 words
  const int wi = wid & 3;
  const int ci = wid >> 2;                          // chunk 0..18431
  const int c   = ci & 7;
  const int nch = (ci >> 3) & 127;
  const int tt  = ci >> 10;                         // kt*9 + tap
  const int tap = tt % 9;
  const int kt  = tt / 9;
  const int k  = kt * 128 + nch;
  const int c0 = c * 16 + wi * 4;
  const int base = (k * CIN + c0) * 9 + tap;        // OIHW, 3x3=9 taps
  const int v0 = wgt[base];
  const int v1 = wgt[base + 9];
  const int v2 = wgt[base + 18];
  const int v3 = wgt[base + 27];
  reinterpret_cast<int*>(wq)[wid] =
      (v0 & 0xff) | ((v1 & 0xff) << 8) | ((v2 & 0xff) << 16) | (v3 << 24);
}

// ---------------- conv: MFMA implicit GEMM ----------------
// grid (28 rowpairs, 32 n, 2 kt), 256 threads (4 waves).
// Block: 128 out-ch (kt half) x 128 px (2 rows x 64). Wave (wc,wp): 64 ch x 64 px.
// Weights: register double-buffer, prefetched one tap ahead from global (L2-hot).
// Pixels: LDS, staged once, XOR-swizzled. One barrier total.
__global__ __launch_bounds__(256, 3) void conv_kernel(const int8_t* __restrict__ xp,
                                                      const int8_t* __restrict__ wq,
                                                      const int* __restrict__ bias,
                                                      const float* __restrict__ wscale,
                                                      int* __restrict__ out) {
  __shared__ __align__(16) int8_t lx[240 * CIN];        // 30,720 B (4 rows + OOB slack)
  __shared__ int   bsh[128];
  __shared__ float ssh[128];

  const int tid = threadIdx.x;
  const int h0 = blockIdx.x * 2;
  const int n_img = blockIdx.y;
  const int kt = blockIdx.z;

  const int lane = tid & 63;
  const int wid = tid >> 6;
  const int wc = wid & 1;            // which 64-ch half
  const int wp = wid >> 1;           // which output row
  const int p0 = lane & 31;
  const int half = lane >> 5;

  const int8_t* xg = xp + ((size_t)(n_img * HP) + h0) * ROWB;
  const int8_t* wbase = wq + (size_t)kt * 147456;

  // ---- stage pixels: 4 padded rows, flat-pixel XOR chunk swizzle ----
  #pragma unroll
  for (int it = 0; it < 8; ++it) {
    const int i = it * 256 + tid;                       // chunk slot < 1856
    if (i < 4 * HP * 8) {
      const int pf = i >> 3;
      const int cc = (i & 7) ^ (pf & 7);
      const int4 v = *reinterpret_cast<const int4*>(xg + pf * CIN + (cc << 4));
      *reinterpret_cast<int4*>(lx + i * 16) = v;
    }
  }
  // ---- requant table ----
  if (tid < 128) {
    const int ch = kt * 128 + tid;
    bsh[tid] = bias[ch];
    ssh[tid] = (0.02f * wscale[ch]) / 0.05f;
  }
  __syncthreads();

  v16i acc[2][2];                    // [mt: ch tile][nt: px tile]
  #pragma unroll
  for (int mt = 0; mt < 2; ++mt)
    #pragma unroll
    for (int nt = 0; nt < 2; ++nt)
      #pragma unroll
      for (int e = 0; e < 16; ++e) acc[mt][nt][e] = 0;

  // weight fragment base: ch = wc*64 + mt*32 + p0, k-chunk = half + 2*ks
  const int8_t* ab = wbase + (wc * 64 + p0) * 128 + half * 16;
  const int base0 = wp * HP + p0;    // flat pixel (row wp, px p0)

  v4i wf[2][8];                      // [buf][ks*2 + mt] tap double-buffer
  #pragma unroll
  for (int ks = 0; ks < 4; ++ks)
    #pragma unroll
    for (int mt = 0; mt < 2; ++mt)
      wf[0][ks * 2 + mt] = *reinterpret_cast<const v4i*>(ab + mt * 4096 + ks * 32);

  #pragma unroll
  for (int tap = 0; tap < 9; ++tap) {
    const int cb = tap & 1, nb = cb ^ 1;
    if (tap < 8) {                   // prefetch next tap's weights into other buffer
      #pragma unroll
      for (int ks = 0; ks < 4; ++ks)
        #pragma unroll
        for (int mt = 0; mt < 2; ++mt)
          wf[nb][ks * 2 + mt] =
              *reinterpret_cast<const v4i*>(ab + (tap + 1) * 16384 + mt * 4096 + ks * 32);
    }
    const int kh = tap / 3, kw = tap % 3;
    const int pfb = base0 + kh * HP + kw;
    const int keya = (pfb & 7) << 4;

    #pragma unroll
    for (int ks = 0; ks < 4; ++ks) {
      const int ch = (ks * 2 + half) << 4;
      const v4i pf0 = *reinterpret_cast<const v4i*>(lx + pfb * CIN + (ch ^ keya));
      const v4i pf1 = *reinterpret_cast<const v4i*>(lx + (pfb + 32) * CIN + (ch ^ keya));
      acc[0][0] = __builtin_amdgcn_mfma_i32_32x32x32_i8(wf[cb][ks * 2 + 0], pf0, acc[0][0], 0, 0, 0);
      acc[0][1] = __builtin_amdgcn_mfma_i32_32x32x32_i8(wf[cb][ks * 2 + 0], pf1, acc[0][1], 0, 0, 0);
      acc[1][0] = __builtin_amdgcn_mfma_i32_32x32x32_i8(wf[cb][ks * 2 + 1], pf0, acc[1][0], 0, 0, 0);
      acc[1][1] = __builtin_amdgcn_mfma_i32_32x32x32_i8(wf[cb][ks * 2 + 1], pf1, acc[1][1], 0, 0, 0);
    }
  }

  // ---- epilogue: D row = out-ch = (r&3)+8*(r>>2)+4*half (+mt*32), col = pixel ----
  const int h = h0 + wp;
  #pragma unroll
  for (int mt = 0; mt < 2; ++mt) {
    #pragma unroll
    for (int r = 0; r < 16; ++r) {
      const int mrow = (r & 3) + 8 * (r >> 2) + 4 * half;
      const int cl = wc * 64 + mt * 32 + mrow;        // ch local to kt
      const int bi = bsh[cl];
      const float sc = ssh[cl];
      int* ob = out + (((size_t)(n_img * KOUT + kt * 128 + cl)) * HO + h) * WO;
      #pragma unroll
      for (int nt = 0; nt < 2; ++nt) {
        const int w = nt * 32 + p0;
        if (w < WO) {
          float v = (float)(acc[mt][nt][r] + bi) * sc;
          v = rintf(v);
          v = fminf(fmaxf(v, -128.0f), 127.0f);
          ob[w] = (int)v;
        }
      }
    }
  }
}

extern "C" void kernel_launch(void* const* d_in, const int* in_sizes, int n_in,
                              void* d_out, int out_size, void* d_ws, size_t ws_size,
                              hipStream_t stream) {
  const int* x = (const int*)d_in[0];
  const int* wgt = (const int*)d_in[1];
  const int* bias = (const int*)d_in[2];
  const float* wscale = (const float*)d_in[3];
  int* out = (int*)d_out;

  int8_t* xp = (int8_t*)d_ws;                               // 13,780,992 B
  int8_t* wq = (int8_t*)d_ws + (size_t)NB * HP * ROWB;      // 294,912 B

  pack_x_kernel<<<dim3(HP, NB), 256, 0, stream>>>(x, xp);
  pack_w_kernel<<<288, 256, 0, stream>>>(wgt, wq);
  conv_kernel<<<dim3(28, 32, 2), 256, 0, stream>>>(xp, wq, bias, wscale, out);
}

// Round 6
// 191.679 us; speedup vs baseline: 4.7067x; 1.1368x over previous
//
#include <hip/hip_runtime.h>
#include <hip/hip_bf16.h>
#include <stdint.h>

// QuantizedConv2d int8: x (32,128,56,56), w (256,128,3,3), pad 1, stride 1.
// Implicit GEMM on v_mfma_i32_32x32x32_i8. M=out-ch, N=pixels, K=9*128=1152.
// R6: wave tile 64ch x 128px (2 rows), block 128ch x 4 rows. Tap-pair loop
// (#pragma unroll 1) with named register double-buffer + sched_barrier fences
// so weight loads for tap t+1 stay in flight across tap t's 32 MFMAs.

#define NB   32
#define CIN  128
#define HO   56
#define WO   56
#define KOUT 256
#define HP   58
#define ROWB (HP * CIN)          // 7424 bytes per padded row

typedef int v4i  __attribute__((ext_vector_type(4)));
typedef int v16i __attribute__((ext_vector_type(16)));

// ---------------- pack x: NCHW int32 -> padded NHWC int8, borders written ----
__global__ __launch_bounds__(256) void pack_x_kernel(const int* __restrict__ x,
                                                     int8_t* __restrict__ xp) {
  __shared__ int tile[WO][33];
  const int tid = threadIdx.x;
  const int r = blockIdx.x;          // padded row 0..57
  const int n = blockIdx.y;
  const int tx = tid & 63;
  const int ty = tid >> 6;
  const bool interior = (r >= 1) && (r <= HO);

  if (interior && tx < WO) {
    const int h = r - 1;
    #pragma unroll
    for (int c0 = 0; c0 < CIN; c0 += 16) {
      const int c = c0 + ty * 4;
      const int base = ((n * CIN + c) * HO + h) * WO + tx;
      const int v0 = x[base];
      const int v1 = x[base + HO * WO];
      const int v2 = x[base + 2 * HO * WO];
      const int v3 = x[base + 3 * HO * WO];
      tile[tx][c >> 2] = (v0 & 0xff) | ((v1 & 0xff) << 8) | ((v2 & 0xff) << 16) | (v3 << 24);
    }
  }
  __syncthreads();
  #pragma unroll
  for (int it = 0; it < 8; ++it) {
    const int i = it * 256 + tid;
    if (i < HP * 32) {
      const int w = i >> 5;
      const int c4 = i & 31;
      const int v = (interior && w >= 1 && w <= WO) ? tile[w - 1][c4] : 0;
      *reinterpret_cast<int*>(xp + ((size_t)(n * HP + r) * HP + w) * CIN + c4 * 4) = v;
    }
  }
}

// ---------------- pack w: OIHW int32 -> [kt(2)][tap(9)][n(128)][chunk(8)] 16B ----
__global__ __launch_bounds__(256) void pack_w_kernel(const int* __restrict__ wgt,
                                                     int8_t* __restrict__ wq) {
  const int wid = blockIdx.x * 256 + threadIdx.x;   // 0..73727 int32 words
  const int wi = wid & 3;
  const int ci = wid >> 2;                          // chunk 0..18431
  const int c   = ci & 7;
  const int nch = (ci >> 3) & 127;
  const int tt  = ci >> 10;                         // kt*9 + tap
  const int tap = tt % 9;
  const int kt  = tt / 9;
  const int k  = kt * 128 + nch;
  const int c0 = c * 16 + wi * 4;
  const int base = (k * CIN + c0) * 9 + tap;        // OIHW, 3x3=9 taps
  const int v0 = wgt[base];
  const int v1 = wgt[base + 9];
  const int v2 = wgt[base + 18];
  const int v3 = wgt[base + 27];
  reinterpret_cast<int*>(wq)[wid] =
      (v0 & 0xff) | ((v1 & 0xff) << 8) | ((v2 & 0xff) << 16) | (v3 << 24);
}

// ---------------- conv ----------------
// grid (14 rowquads, 32 n, 2 kt), 256 threads = 4 waves (wc: ch-half, wr: row-pair).
// Wave: 64 ch x 128 px (2 rows x 64). acc 2mt x 2rloc x 2nt x v16i = 128 regs.
__global__ __launch_bounds__(256, 2) void conv_kernel(const int8_t* __restrict__ xp,
                                                      const int8_t* __restrict__ wq,
                                                      const int* __restrict__ bias,
                                                      const float* __restrict__ wscale,
                                                      int* __restrict__ out) {
  __shared__ __align__(16) int8_t lx[6 * HP * 8 * 16];   // 44,544 B: 6 padded rows
  __shared__ int   bsh[128];
  __shared__ float ssh[128];

  const int tid = threadIdx.x;
  const int h0 = blockIdx.x * 4;
  const int n_img = blockIdx.y;
  const int kt = blockIdx.z;

  const int lane = tid & 63;
  const int wid = tid >> 6;
  const int wc = wid & 1;            // 64-ch half
  const int wr = wid >> 1;           // row pair
  const int p0 = lane & 31;
  const int half = lane >> 5;

  const int8_t* xg = xp + ((size_t)(n_img * HP) + h0) * ROWB;
  const int8_t* wbase = wq + (size_t)kt * 147456;

  // ---- stage pixels: 6 padded rows, two-phase (all loads in flight) ----
  v4i tmp[11];
  #pragma unroll
  for (int it = 0; it < 11; ++it) {
    const int i = it * 256 + tid;                        // chunk slot < 2784
    if (i < 6 * HP * 8) {
      const int pf = i >> 3;
      const int cc = (i & 7) ^ (pf & 7);
      tmp[it] = *reinterpret_cast<const v4i*>(xg + pf * CIN + (cc << 4));
    }
  }
  #pragma unroll
  for (int it = 0; it < 11; ++it) {
    const int i = it * 256 + tid;
    if (i < 6 * HP * 8)
      *reinterpret_cast<v4i*>(lx + i * 16) = tmp[it];
  }
  if (tid < 128) {
    const int ch = kt * 128 + tid;
    bsh[tid] = bias[ch];
    ssh[tid] = (0.02f * wscale[ch]) / 0.05f;
  }
  __syncthreads();

  v16i acc[2][2][2];                  // [mt][rloc][nt]
  #pragma unroll
  for (int mt = 0; mt < 2; ++mt)
    #pragma unroll
    for (int rl = 0; rl < 2; ++rl)
      #pragma unroll
      for (int nt = 0; nt < 2; ++nt)
        #pragma unroll
        for (int e = 0; e < 16; ++e) acc[mt][rl][nt][e] = 0;

  // weight fragment base: ch = wc*64 + mt*32 + p0, k-chunk = half + 2*ks
  const int8_t* ab = wbase + (wc * 64 + p0) * 128 + half * 16;

  v4i wfA[8], wfB[8];                 // [ks*2 + mt]

#define PREFETCH(tapn, buf)                                                     \
  {                                                                             \
    const int8_t* tb = ab + (tapn) * 16384;                                     \
    _Pragma("unroll")                                                           \
    for (int ks = 0; ks < 4; ++ks)                                              \
      _Pragma("unroll")                                                         \
      for (int mt = 0; mt < 2; ++mt)                                            \
        buf[ks * 2 + mt] = *reinterpret_cast<const v4i*>(tb + mt * 4096 + ks * 32); \
  }

#define COMPUTE(tapn, buf)                                                      \
  {                                                                             \
    const int kh = (tapn) / 3, kw = (tapn) % 3;                                 \
    _Pragma("unroll")                                                           \
    for (int ks = 0; ks < 4; ++ks) {                                            \
      const int chb = (ks * 2 + half) << 4;                                     \
      _Pragma("unroll")                                                         \
      for (int rl = 0; rl < 2; ++rl) {                                          \
        _Pragma("unroll")                                                       \
        for (int nt = 0; nt < 2; ++nt) {                                        \
          const int pf = (wr * 2 + rl + kh) * HP + kw + nt * 32 + p0;           \
          const v4i b = *reinterpret_cast<const v4i*>(                          \
              lx + pf * CIN + (chb ^ ((pf & 7) << 4)));                         \
          acc[0][rl][nt] = __builtin_amdgcn_mfma_i32_32x32x32_i8(               \
              buf[ks * 2 + 0], b, acc[0][rl][nt], 0, 0, 0);                     \
          acc[1][rl][nt] = __builtin_amdgcn_mfma_i32_32x32x32_i8(               \
              buf[ks * 2 + 1], b, acc[1][rl][nt], 0, 0, 0);                     \
        }                                                                       \
      }                                                                         \
    }                                                                           \
  }

  PREFETCH(0, wfA);
  #pragma unroll 1
  for (int t2 = 0; t2 < 4; ++t2) {
    const int tap = 2 * t2;
    PREFETCH(tap + 1, wfB);
    __builtin_amdgcn_sched_barrier(0);
    COMPUTE(tap, wfA);
    __builtin_amdgcn_sched_barrier(0);
    PREFETCH(tap + 2, wfA);
    __builtin_amdgcn_sched_barrier(0);
    COMPUTE(tap + 1, wfB);
    __builtin_amdgcn_sched_barrier(0);
  }
  COMPUTE(8, wfA);

  // ---- epilogue: D row = out-ch = mt*32 + (r&3)+8*(r>>2)+4*half, col = pixel ----
  #pragma unroll
  for (int mt = 0; mt < 2; ++mt) {
    #pragma unroll
    for (int r = 0; r < 16; ++r) {
      const int cl = wc * 64 + mt * 32 + (r & 3) + 8 * (r >> 2) + 4 * half;
      const int bi = bsh[cl];
      const float sc = ssh[cl];
      #pragma unroll
      for (int rl = 0; rl < 2; ++rl) {
        const int h = h0 + wr * 2 + rl;
        int* ob = out + (((size_t)(n_img * KOUT + kt * 128 + cl)) * HO + h) * WO;
        #pragma unroll
        for (int nt = 0; nt < 2; ++nt) {
          const int w = nt * 32 + p0;
          if (w < WO) {
            float v = (float)(acc[mt][rl][nt][r] + bi) * sc;
            v = rintf(v);
            v = fminf(fmaxf(v, -128.0f), 127.0f);
            ob[w] = (int)v;
          }
        }
      }
    }
  }
#undef PREFETCH
#undef COMPUTE
}

extern "C" void kernel_launch(void* const* d_in, const int* in_sizes, int n_in,
                              void* d_out, int out_size, void* d_ws, size_t ws_size,
                              hipStream_t stream) {
  const int* x = (const int*)d_in[0];
  const int* wgt = (const int*)d_in[1];
  const int* bias = (const int*)d_in[2];
  const float* wscale = (const float*)d_in[3];
  int* out = (int*)d_out;

  int8_t* xp = (int8_t*)d_ws;                               // 13,780,992 B
  int8_t* wq = (int8_t*)d_ws + (size_t)NB * HP * ROWB;      // 294,912 B

  pack_x_kernel<<<dim3(HP, NB), 256, 0, stream>>>(x, xp);
  pack_w_kernel<<<288, 256, 0, stream>>>(wgt, wq);
  conv_kernel<<<dim3(14, 32, 2), 256, 0, stream>>>(xp, wq, bias, wscale, out);
}